// Round 1
// baseline (61893.982 us; speedup 1.0000x reference)
//
#include <hip/hip_runtime.h>
#include <hip/hip_bf16.h>
#include <cstdint>
#include <cstddef>

// ---------------------------------------------------------------------------
// RNN-T greedy decoder, MI355X persistent cooperative kernel.
//
// Design notes (R1):
//  - 400 sequential steps; only cross-batch coupling in the reference is the
//    scalar `finished = all(time==eos)` flag. We run FREE-RUNNING (ignore
//    finished), log token writes + r[b] = first step time[b]==eos[b], then fix
//    up tokens/out_lens and replicate ys[s*+1] over s>=s*+2 after one global
//    barrier (free-running == reference for all steps <= s* = max_b r[b]).
//  - E0 = embed@w_ih0+b0 precomputed (29x1280) -> LSTM0 input matmul is a
//    table lookup.  fi@w_f cached per-b, recomputed only when time[b] moves.
//  - 256 WGs x 640 thr, 1 WG/CU (140KB LDS each). Partition: 4 batch-groups
//    (32 b each) x 64 column-groups. Weight column slices live in LDS for the
//    whole kernel (weight-stationary). Per step 4 phases with per-batch-group
//    64-WG atomic barriers (groups are independent until the epilogue).
// ---------------------------------------------------------------------------

#define T_DIM 200
#define B_DIM 128
#define FH 1024
#define PH 320
#define G4 1280
#define JH 512
#define NV 29
#define BLANKSYM 28
#define NSTEPS 400
#define MAXLEN 256

#define NWG 256
#define NTHR 640
#define BPG 32      // batch elems per batch-group
#define WGPG 64     // workgroups per batch-group

// ---- workspace float offsets ----
enum : int {
  H0_O  = 0,
  C0_O  = H0_O  + B_DIM*PH,
  H1_O  = C0_O  + B_DIM*PH,
  C1_O  = H1_O  + B_DIM*PH,
  H0N_O = C1_O  + B_DIM*PH,
  C0N_O = H0N_O + B_DIM*PH,
  H1N_O = C0N_O + B_DIM*PH,
  C1N_O = H1N_O + B_DIM*PH,
  FP_O  = C1N_O + B_DIM*PH,
  JR_O  = FP_O  + B_DIM*JH,
  WSF_TOT = JR_O + B_DIM*JH
};
// ---- workspace int offsets (base = (int*)(wsf + WSF_TOT)) ----
enum : int {
  PREG_O  = 0,
  TIMEI_O = B_DIM,
  TCH_O   = 2*B_DIM,
  R_O     = 3*B_DIM,
  BAR_O   = 4*B_DIM,            // 5 barriers x 64-int padding
  LOG_O   = BAR_O + 5*64,       // [B_DIM][NSTEPS]
  WSI_TOT = LOG_O + B_DIM*NSTEPS
};
// ---- output offsets (floats) ----
enum : int { YS_O = 0, TOK_O = NSTEPS*B_DIM*NV, LEN_O = TOK_O + B_DIM*MAXLEN };

// ---- LDS layout (floats) ----
#define WA_F  (20*322)   // w_hh0 cols [20][322]
#define WB_F  (20*642)   // w_ih1|w_hh1 cols [20][642]
#define WGG_F (8*322)    // w_g cols [8][322]
#define E0_F  (29*20)    // E0 slice
#define HB_F  (32*322)   // staged h slice
#define GB_F  640        // gate buffer / ybuf
#define FR_F  1024       // f-row / JR stage / token buf
#define RED_F 640        // reductions / log buf
#define IB_F  64         // ints: [0..31] pre_g cache, [32] nb flag, [34] sstar
#define LDS_FLOATS (WA_F+WB_F+WGG_F+E0_F+HB_F+GB_F+FR_F+RED_F+IB_F)

__device__ __forceinline__ float sigm(float x) { return 1.0f / (1.0f + expf(-x)); }

// device-scope sense-free generation barrier
__device__ __forceinline__ void bar_sync(int* bar, int count) {
  __syncthreads();
  if (threadIdx.x == 0) {
    __threadfence();
    int g = __hip_atomic_load(bar + 1, __ATOMIC_RELAXED, __HIP_MEMORY_SCOPE_AGENT);
    int a = __hip_atomic_fetch_add(bar, 1, __ATOMIC_ACQ_REL, __HIP_MEMORY_SCOPE_AGENT);
    if (a == count - 1) {
      __hip_atomic_store(bar, 0, __ATOMIC_RELAXED, __HIP_MEMORY_SCOPE_AGENT);
      __hip_atomic_store(bar + 1, g + 1, __ATOMIC_RELEASE, __HIP_MEMORY_SCOPE_AGENT);
    } else {
      while (__hip_atomic_load(bar + 1, __ATOMIC_ACQUIRE, __HIP_MEMORY_SCOPE_AGENT) == g) {
        __builtin_amdgcn_s_sleep(2);
      }
    }
    __threadfence();
  }
  __syncthreads();
}

// stage a [32][PH] slice of state into LDS hb[32][322] (pad 2 -> 2-way bank, free)
__device__ __forceinline__ void stage32(float* __restrict__ hb,
                                        const float* __restrict__ src, int tid) {
  for (int i = tid; i < BPG * (PH/2); i += NTHR) {
    int b  = i / (PH/2);
    int k2 = i - b * (PH/2);
    *(float2*)(hb + b*322 + 2*k2) = *(const float2*)(src + b*PH + 2*k2);
  }
}

__device__ __forceinline__ float dot320(const float* __restrict__ h,
                                        const float* __restrict__ w) {
  float a0 = 0.f, a1 = 0.f, a2 = 0.f, a3 = 0.f;
  const float2* h2 = (const float2*)h;
  const float2* w2 = (const float2*)w;
#pragma unroll 4
  for (int k = 0; k < 160; k += 4) {
    float2 x0 = h2[k+0], x1 = h2[k+1], x2 = h2[k+2], x3 = h2[k+3];
    float2 y0 = w2[k+0], y1 = w2[k+1], y2 = w2[k+2], y3 = w2[k+3];
    a0 = fmaf(x0.x, y0.x, a0); a0 = fmaf(x0.y, y0.y, a0);
    a1 = fmaf(x1.x, y1.x, a1); a1 = fmaf(x1.y, y1.y, a1);
    a2 = fmaf(x2.x, y2.x, a2); a2 = fmaf(x2.y, y2.y, a2);
    a3 = fmaf(x3.x, y3.x, a3); a3 = fmaf(x3.y, y3.y, a3);
  }
  return (a0 + a1) + (a2 + a3);
}

__global__ void init_k(float* wsf, int* wsi) {
  int i = blockIdx.x * blockDim.x + threadIdx.x;
  int n = blockDim.x * gridDim.x;
  for (int x = i; x < 4 * B_DIM * PH; x += n) wsf[x] = 0.f;  // h0,c0,h1,c1
  for (int x = i; x < B_DIM; x += n) {
    wsi[PREG_O + x] = 0;
    wsi[TIMEI_O + x] = 0;
    wsi[TCH_O + x] = 1;        // force Fp compute at step 0
    wsi[R_O + x] = NSTEPS;     // sentinel: never reached eos
  }
  for (int x = i; x < 5*64; x += n) wsi[BAR_O + x] = 0;
}

__global__ void __launch_bounds__(NTHR) decode_main(
    const float* __restrict__ f, const int* __restrict__ f_lens,
    const float* __restrict__ embed,
    const float* __restrict__ w_ih0, const float* __restrict__ w_hh0,
    const float* __restrict__ b0,
    const float* __restrict__ w_ih1, const float* __restrict__ w_hh1,
    const float* __restrict__ b1,
    const float* __restrict__ w_f, const float* __restrict__ w_g,
    const float* __restrict__ b_j,
    const float* __restrict__ w_o, const float* __restrict__ b_o,
    float* __restrict__ out, float* __restrict__ wsf, int* __restrict__ wsi) {
  extern __shared__ float smem[];
  float* wA   = smem;
  float* wB   = wA + WA_F;
  float* wGl  = wB + WB_F;
  float* e0   = wGl + WGG_F;
  float* hb   = e0 + E0_F;
  float* gbuf = hb + HB_F;
  float* frow = gbuf + GB_F;
  float* red  = frow + FR_F;
  int*   ibuf = (int*)(red + RED_F);

  const int tid = threadIdx.x;
  const int wg  = blockIdx.x;
  const int bg  = wg >> 6;       // batch-group 0..3
  const int cg  = wg & 63;       // column-group 0..63
  const int b0i = bg * BPG;
  int* barp = wsi + BAR_O + bg * 64;
  int* barg = wsi + BAR_O + 4 * 64;

  // ---------------- prologue: load weight slices into LDS ----------------
  // wA: w_hh0 columns {gate*320 + cg*5+u}, ci = gate*5+u
  for (int i = tid; i < 20 * PH; i += NTHR) {
    int ci = i / PH, k = i - ci * PH;
    int col = (ci / 5) * PH + cg * 5 + (ci % 5);
    wA[ci * 322 + k] = w_hh0[(size_t)k * G4 + col];
  }
  // wB: [w_ih1 ; w_hh1] columns (K=640)
  for (int i = tid; i < 20 * 2 * PH; i += NTHR) {
    int ci = i / (2 * PH), k = i - ci * 2 * PH;
    int col = (ci / 5) * PH + cg * 5 + (ci % 5);
    wB[ci * 642 + k] = (k < PH) ? w_ih1[(size_t)k * G4 + col]
                                : w_hh1[(size_t)(k - PH) * G4 + col];
  }
  // wG: w_g columns cg*8..cg*8+7
  for (int i = tid; i < 8 * PH; i += NTHR) {
    int j = i / PH, k = i - j * PH;
    wGl[j * 322 + k] = w_g[(size_t)k * JH + cg * 8 + j];
  }
  // E0 slice: E0[v][ci] = b0[col] + embed[v] . w_ih0[:,col]
  for (int i = tid; i < 29 * 20; i += NTHR) {
    int v = i / 20, ci = i - v * 20;
    int col = (ci / 5) * PH + cg * 5 + (ci % 5);
    float acc = b0[col];
    for (int k = 0; k < PH; ++k)
      acc = fmaf(embed[v * PH + k], w_ih0[(size_t)k * G4 + col], acc);
    e0[v * 20 + ci] = acc;
  }
  __syncthreads();

  // per-b decoder scalar state (thread 0 of b-owner WGs: cg<32 -> b = b0i+cg)
  int time_reg = 0, len_reg = 0, r_reg = NSTEPS, eos_reg = 0;
  if (cg < BPG && tid == 0) eos_reg = f_lens[b0i + cg] - 1;

  // ---------------- 400 free-running steps ----------------
  for (int s = 0; s < NSTEPS; ++s) {
    // ===== Phase A: LSTM0 gates + elementwise =====
    stage32(hb, wsf + H0_O + (size_t)b0i * PH, tid);
    if (tid < BPG) ibuf[tid] = wsi[PREG_O + b0i + tid];
    __syncthreads();
    {
      int b = tid & 31, ci = tid >> 5;           // 640 dots: 32 b x 20 cols
      float acc = dot320(hb + b * 322, wA + ci * 322);
      gbuf[b * 20 + ci] = acc + e0[ibuf[b] * 20 + ci];
    }
    __syncthreads();
    if (tid < 160) {
      int b = tid & 31, u = tid >> 5;
      int p = cg * 5 + u, gb = b0i + b;
      float gi = gbuf[b*20 + u],      gf = gbuf[b*20 + 5 + u];
      float gg = gbuf[b*20 + 10 + u], go = gbuf[b*20 + 15 + u];
      float c  = wsf[C0_O + gb * PH + p];
      float cn = sigm(gf) * c + sigm(gi) * tanhf(gg);
      float hn = sigm(go) * tanhf(cn);
      wsf[H0N_O + gb * PH + p] = hn;
      wsf[C0N_O + gb * PH + p] = cn;
    }
    bar_sync(barp, WGPG);

    // ===== Phase B: LSTM1 gates + elementwise =====
    float accB;
    {
      stage32(hb, wsf + H0N_O + (size_t)b0i * PH, tid);
      __syncthreads();
      int b = tid & 31, ci = tid >> 5;
      accB = dot320(hb + b * 322, wB + ci * 642);
      __syncthreads();                       // all reads done before restage
      stage32(hb, wsf + H1_O + (size_t)b0i * PH, tid);
      __syncthreads();
      int col = (ci / 5) * PH + cg * 5 + (ci % 5);
      accB += dot320(hb + b * 322, wB + ci * 642 + PH);
      gbuf[b * 20 + ci] = accB + b1[col];
    }
    __syncthreads();
    if (tid < 160) {
      int b = tid & 31, u = tid >> 5;
      int q = cg * 5 + u, gb = b0i + b;
      float gi = gbuf[b*20 + u],      gf = gbuf[b*20 + 5 + u];
      float gg = gbuf[b*20 + 10 + u], go = gbuf[b*20 + 15 + u];
      float c  = wsf[C1_O + gb * PH + q];
      float cn = sigm(gf) * c + sigm(gi) * tanhf(gg);
      float hn = sigm(go) * tanhf(cn);
      wsf[H1N_O + gb * PH + q] = hn;
      wsf[C1N_O + gb * PH + q] = cn;
    }
    bar_sync(barp, WGPG);

    // ===== Phase C: Fp refresh (rare) + joint relu =====
    for (int bb = 0; bb < BPG; ++bb) {
      int gb = b0i + bb;
      if (wsi[TCH_O + gb]) {                 // WG-uniform branch
        int t = wsi[TIMEI_O + gb];
        const float* fr = f + ((size_t)t * B_DIM + gb) * FH;
        for (int i = tid; i < FH; i += NTHR) frow[i] = fr[i];
        __syncthreads();
        if (tid < 512) {
          int j = tid & 7, kg = tid >> 3;
          float part = 0.f;
#pragma unroll 4
          for (int it = 0; it < FH / 64; ++it) {
            int kk = kg + it * 64;
            part = fmaf(frow[kk], w_f[(size_t)kk * JH + cg * 8 + j], part);
          }
          red[tid] = part;
        }
        __syncthreads();
        if (tid < 8) {
          float sum = 0.f;
          for (int kg = 0; kg < 64; ++kg) sum += red[kg * 8 + tid];
          wsf[FP_O + gb * JH + cg * 8 + tid] = sum + b_j[cg * 8 + tid];
        }
        __syncthreads();
      }
    }
    stage32(hb, wsf + H1N_O + (size_t)b0i * PH, tid);
    __syncthreads();
    if (tid < 256) {
      int b = tid & 31, j = tid >> 5;
      int gb = b0i + b, jg = cg * 8 + j;
      float acc = dot320(hb + b * 322, wGl + j * 322);
      float v = wsf[FP_O + gb * JH + jg] + acc;
      wsf[JR_O + gb * JH + jg] = v > 0.f ? v : 0.f;
    }
    bar_sync(barp, WGPG);

    // ===== Phase D: logits, argmax, state commit (b-owner WGs) =====
    if (cg < BPG) {
      int b = b0i + cg;
      for (int i = tid; i < JH; i += NTHR) frow[i] = wsf[JR_O + b * JH + i];
      __syncthreads();
      if (tid < 512) {
        int v = tid & 31, jg = tid >> 5;
        float part = 0.f;
        if (v < NV) {
          const float* wop = w_o + (size_t)(jg * 32) * NV + v;
#pragma unroll 8
          for (int jj = 0; jj < 32; ++jj)
            part = fmaf(frow[jg * 32 + jj], wop[(size_t)jj * NV], part);
        }
        red[tid] = part;
      }
      __syncthreads();
      if (tid < NV) {
        float y = b_o[tid];
#pragma unroll
        for (int jg = 0; jg < 16; ++jg) y += red[jg * 32 + tid];
        out[((size_t)s * B_DIM + b) * NV + tid] = y;
        gbuf[tid] = y;
      }
      __syncthreads();
      if (tid == 0) {
        float best = gbuf[0]; int bi = 0;
        for (int v = 1; v < NV; ++v) {       // np.argmax: first max
          float yv = gbuf[v];
          if (yv > best) { best = yv; bi = v; }
        }
        int nb = (bi != BLANKSYM) ? 1 : 0;
        unsigned logw = 0u;
        if (nb) {
          int pos = len_reg < (MAXLEN - 1) ? len_reg : (MAXLEN - 1);
          logw = 0x80000000u | ((unsigned)pos << 8) | (unsigned)bi;
          len_reg++;
          wsi[PREG_O + b] = bi;
        }
        wsi[LOG_O + b * NSTEPS + s] = (int)logw;
        int tnew = time_reg + (nb ? 0 : 1);
        if (tnew > eos_reg) tnew = eos_reg;
        wsi[TCH_O + b] = (tnew != time_reg) ? 1 : 0;
        wsi[TIMEI_O + b] = tnew;
        if (r_reg == NSTEPS && tnew == eos_reg) r_reg = s;
        time_reg = tnew;
        ibuf[32] = nb;
      }
      __syncthreads();
      if (ibuf[32]) {                        // commit h/c state for this b
        int b2 = b;
        for (int i = tid; i < PH; i += NTHR) {
          wsf[H0_O + b2 * PH + i] = wsf[H0N_O + b2 * PH + i];
          wsf[C0_O + b2 * PH + i] = wsf[C0N_O + b2 * PH + i];
          wsf[H1_O + b2 * PH + i] = wsf[H1N_O + b2 * PH + i];
          wsf[C1_O + b2 * PH + i] = wsf[C1N_O + b2 * PH + i];
        }
      }
      __syncthreads();
    }
    bar_sync(barp, WGPG);
  }

  // ---------------- epilogue: finished-flag fixup ----------------
  if (cg < BPG && tid == 0) wsi[R_O + b0i + cg] = r_reg;
  bar_sync(barg, NWG);

  // s* = max_b r[b], computed redundantly in every WG
  if (tid < B_DIM) ((int*)red)[tid] = wsi[R_O + tid];
  __syncthreads();
  if (tid == 0) {
    int m = 0;
    for (int i = 0; i < B_DIM; ++i) m = max(m, ((int*)red)[i]);
    ibuf[34] = m;
  }
  __syncthreads();
  const int sstar = ibuf[34];
  __syncthreads();

  // ys tail: steps >= sstar+2 all equal ys[sstar+1]
  if (sstar <= NSTEPS - 3) {
    const size_t srcbase = (size_t)(sstar + 1) * B_DIM * NV;
    const size_t start = (size_t)(sstar + 2) * B_DIM * NV;
    const size_t total = (size_t)(NSTEPS - 2 - sstar) * B_DIM * NV;
    for (size_t i = (size_t)wg * NTHR + tid; i < total; i += (size_t)NWG * NTHR) {
      size_t r = i % (size_t)(B_DIM * NV);
      out[start + i] = out[srcbase + r];
    }
  }

  // tokens + out_lens: replay log entries for steps <= min(sstar, 399)
  if (wg < B_DIM) {
    int b = wg;
    int* lbuf = (int*)red;
    for (int i = tid; i < NSTEPS; i += NTHR) lbuf[i] = wsi[LOG_O + b * NSTEPS + i];
    if (tid < MAXLEN) frow[tid] = (float)BLANKSYM;
    __syncthreads();
    if (tid == 0) {
      int len = 0;
      int smax = sstar < NSTEPS - 1 ? sstar : NSTEPS - 1;
      for (int ss = 0; ss <= smax; ++ss) {
        unsigned uw = (unsigned)lbuf[ss];
        if (uw >> 31) {
          int pos = (int)((uw >> 8) & 0xFFu);
          int sym = (int)(uw & 0x1Fu);
          frow[pos] = (float)sym;
          len++;
        }
      }
      ibuf[33] = len;
    }
    __syncthreads();
    if (tid < MAXLEN) out[TOK_O + b * MAXLEN + tid] = frow[tid];
    if (tid == 0) out[LEN_O + b] = (float)ibuf[33];
  }
}

extern "C" void kernel_launch(void* const* d_in, const int* in_sizes, int n_in,
                              void* d_out, int out_size, void* d_ws, size_t ws_size,
                              hipStream_t stream) {
  const float* f      = (const float*)d_in[0];
  const int*   f_lens = (const int*)d_in[1];
  const float* embed  = (const float*)d_in[2];
  const float* w_ih0  = (const float*)d_in[3];
  const float* w_hh0  = (const float*)d_in[4];
  const float* b0     = (const float*)d_in[5];
  const float* w_ih1  = (const float*)d_in[6];
  const float* w_hh1  = (const float*)d_in[7];
  const float* b1     = (const float*)d_in[8];
  const float* w_f    = (const float*)d_in[9];
  const float* w_g    = (const float*)d_in[10];
  const float* b_j    = (const float*)d_in[11];
  const float* w_o    = (const float*)d_in[12];
  const float* b_o    = (const float*)d_in[13];
  float* out = (float*)d_out;
  float* wsf = (float*)d_ws;
  int*   wsi = (int*)(wsf + WSF_TOT);

  // allow >64KB dynamic LDS (idempotent; not a stream op, capture-safe)
  hipFuncSetAttribute((const void*)decode_main,
                      hipFuncAttributeMaxDynamicSharedMemorySize,
                      (int)(LDS_FLOATS * sizeof(float)));

  init_k<<<64, 256, 0, stream>>>(wsf, wsi);
  decode_main<<<dim3(NWG), dim3(NTHR), LDS_FLOATS * sizeof(float), stream>>>(
      f, f_lens, embed, w_ih0, w_hh0, b0, w_ih1, w_hh1, b1,
      w_f, w_g, b_j, w_o, b_o, out, wsf, wsi);
}

// Round 3
// 37940.582 us; speedup vs baseline: 1.6313x; 1.6313x over previous
//
#include <hip/hip_runtime.h>
#include <hip/hip_bf16.h>
#include <cstdint>
#include <cstddef>

// ---------------------------------------------------------------------------
// RNN-T greedy decoder, MI355X persistent cooperative kernel.  R2 (resubmit;
// R2 bench was lost to a GPU-acquisition timeout).
//
//  R1 post-mortem: 151us/step, VALUBusy 9% -> time went to the contended
//  single-counter atomic barrier (64-way same-address RMW ~20-30us each, x4
//  per step).  R2: (1) flag-array barrier (per-WG release store + parallel
//  relaxed polling, no RMW); (2) per-b scalar state packed [B][4] and loaded
//  with one coalesced read; (3) ping-pong h/c buffers selected by per-b idx
//  bit (owner flips it) -> no commit copy.
// ---------------------------------------------------------------------------

#define T_DIM 200
#define B_DIM 128
#define FH 1024
#define PH 320
#define G4 1280
#define JH 512
#define NV 29
#define BLANKSYM 28
#define NSTEPS 400
#define MAXLEN 256

#define NWG 256
#define NTHR 640
#define BPG 32      // batch elems per batch-group
#define WGPG 64     // workgroups per batch-group
#define SB (B_DIM*PH)

// ---- workspace float offsets ----
enum : int {
  H0_O = 0,                 // [2][B][PH] ping-pong
  C0_O = 2*SB,
  H1_O = 4*SB,
  C1_O = 6*SB,
  FP_O = 8*SB,              // [B][JH] cached fi@w_f + b_j
  JR_O = FP_O + B_DIM*JH,   // [B][JH] joint relu
  WSF_TOT = JR_O + B_DIM*JH
};
// ---- workspace int offsets ----
enum : int {
  R_O    = 0,                    // [B] first step time hits eos
  PST_O  = B_DIM,                // [B][4]: preg, idx, tch, timei
  FLAG_O = PST_O + 4*B_DIM,      // [4][WGPG][4] group barrier flags
  GFLAG_O = FLAG_O + 4*WGPG*4,   // [NWG][4] global barrier flags
  LOG_O  = GFLAG_O + NWG*4,      // [B][NSTEPS] token log
  WSI_TOT = LOG_O + B_DIM*NSTEPS
};
// ---- output offsets (floats) ----
enum : int { TOK_O = NSTEPS*B_DIM*NV, LEN_O = TOK_O + B_DIM*MAXLEN };

// ---- LDS layout (floats) ----
#define WA_F  (20*322)   // w_hh0 cols [20][322]
#define WB_F  (20*642)   // w_ih1|w_hh1 cols [20][642]
#define WGG_F (8*322)    // w_g cols [8][322]
#define E0_F  (29*20)    // E0 slice
#define HB_F  (32*322)   // staged h slice
#define GB_F  640        // gate buffer / ybuf
#define FR_F  1024       // f-row / token buf
#define RED_F 640        // reductions / log buf
#define IB_F  160        // ints: [0..31] preg [32..63] idx [64..95] tch
                         //       [96..127] timei [128] nb [129] sstar [130] len
#define LDS_FLOATS (WA_F+WB_F+WGG_F+E0_F+HB_F+GB_F+FR_F+RED_F+IB_F)

__device__ __forceinline__ float sigm(float x) { return 1.0f / (1.0f + expf(-x)); }

// Flag-array barrier: rank stores gen to its own flag (release), 64/256 lanes
// poll all flags relaxed in parallel, one acquire fence after.  No RMW.
__device__ __forceinline__ void bar_flags(int* flags, int nf, int rank, int gen) {
  __syncthreads();   // all waves' stores drained (vmcnt0 precedes s_barrier)
  if (threadIdx.x == 0) {
    __threadfence(); // push this XCD's L2 to agent-visible point
    __hip_atomic_store(flags + rank * 4, gen, __ATOMIC_RELEASE,
                       __HIP_MEMORY_SCOPE_AGENT);
  }
  if (threadIdx.x < nf) {
    while (__hip_atomic_load(flags + threadIdx.x * 4, __ATOMIC_RELAXED,
                             __HIP_MEMORY_SCOPE_AGENT) < gen)
      __builtin_amdgcn_s_sleep(1);
  }
  __syncthreads();
  if (threadIdx.x == 0) __threadfence();  // invalidate stale cached state
  __syncthreads();
}

// stage a [32][PH] slice into hb[32][322], per-b ping-pong buffer select
__device__ __forceinline__ void stage32x(float* __restrict__ hb,
                                         const float* __restrict__ base,
                                         const int* __restrict__ idxv, int sel,
                                         int b0i, int tid) {
  for (int i = tid; i < BPG * (PH/2); i += NTHR) {
    int b  = i / (PH/2);
    int k2 = i - b * (PH/2);
    int bf = idxv[b] ^ sel;
    *(float2*)(hb + b*322 + 2*k2) =
        *(const float2*)(base + ((size_t)bf * B_DIM + b0i + b) * PH + 2*k2);
  }
}

__device__ __forceinline__ float dot320(const float* __restrict__ h,
                                        const float* __restrict__ w) {
  float a0 = 0.f, a1 = 0.f, a2 = 0.f, a3 = 0.f;
  const float2* h2 = (const float2*)h;
  const float2* w2 = (const float2*)w;
#pragma unroll 4
  for (int k = 0; k < 160; k += 4) {
    float2 x0 = h2[k+0], x1 = h2[k+1], x2 = h2[k+2], x3 = h2[k+3];
    float2 y0 = w2[k+0], y1 = w2[k+1], y2 = w2[k+2], y3 = w2[k+3];
    a0 = fmaf(x0.x, y0.x, a0); a0 = fmaf(x0.y, y0.y, a0);
    a1 = fmaf(x1.x, y1.x, a1); a1 = fmaf(x1.y, y1.y, a1);
    a2 = fmaf(x2.x, y2.x, a2); a2 = fmaf(x2.y, y2.y, a2);
    a3 = fmaf(x3.x, y3.x, a3); a3 = fmaf(x3.y, y3.y, a3);
  }
  return (a0 + a1) + (a2 + a3);
}

__global__ void init_k(float* wsf, int* wsi) {
  int i = blockIdx.x * blockDim.x + threadIdx.x;
  int n = blockDim.x * gridDim.x;
  for (int x = i; x < 8 * SB; x += n) wsf[x] = 0.f;  // both ping-pong bufs
  for (int x = i; x < B_DIM; x += n) {
    wsi[R_O + x] = NSTEPS;
    wsi[PST_O + x*4 + 0] = 0;   // preg
    wsi[PST_O + x*4 + 1] = 0;   // idx
    wsi[PST_O + x*4 + 2] = 1;   // tch: force Fp compute at step 0
    wsi[PST_O + x*4 + 3] = 0;   // timei
  }
  for (int x = i; x < 4*WGPG*4 + NWG*4; x += n) wsi[FLAG_O + x] = 0;
}

__global__ void __launch_bounds__(NTHR) decode_main(
    const float* __restrict__ f, const int* __restrict__ f_lens,
    const float* __restrict__ embed,
    const float* __restrict__ w_ih0, const float* __restrict__ w_hh0,
    const float* __restrict__ b0,
    const float* __restrict__ w_ih1, const float* __restrict__ w_hh1,
    const float* __restrict__ b1,
    const float* __restrict__ w_f, const float* __restrict__ w_g,
    const float* __restrict__ b_j,
    const float* __restrict__ w_o, const float* __restrict__ b_o,
    float* __restrict__ out, float* __restrict__ wsf, int* __restrict__ wsi) {
  extern __shared__ float smem[];
  float* wA   = smem;
  float* wB   = wA + WA_F;
  float* wGl  = wB + WB_F;
  float* e0   = wGl + WGG_F;
  float* hb   = e0 + E0_F;
  float* gbuf = hb + HB_F;
  float* frow = gbuf + GB_F;
  float* red  = frow + FR_F;
  int*   ibuf = (int*)(red + RED_F);

  const int tid = threadIdx.x;
  const int wg  = blockIdx.x;
  const int bg  = wg >> 6;       // batch-group 0..3
  const int cg  = wg & 63;       // column-group 0..63
  const int b0i = bg * BPG;
  int* gfl = wsi + FLAG_O + bg * WGPG * 4;   // group barrier flags
  int* afl = wsi + GFLAG_O;                  // global barrier flags

  // ---------------- prologue: load weight slices into LDS ----------------
  for (int i = tid; i < 20 * PH; i += NTHR) {
    int ci = i / PH, k = i - ci * PH;
    int col = (ci / 5) * PH + cg * 5 + (ci % 5);
    wA[ci * 322 + k] = w_hh0[(size_t)k * G4 + col];
  }
  for (int i = tid; i < 20 * 2 * PH; i += NTHR) {
    int ci = i / (2 * PH), k = i - ci * 2 * PH;
    int col = (ci / 5) * PH + cg * 5 + (ci % 5);
    wB[ci * 642 + k] = (k < PH) ? w_ih1[(size_t)k * G4 + col]
                                : w_hh1[(size_t)(k - PH) * G4 + col];
  }
  for (int i = tid; i < 8 * PH; i += NTHR) {
    int j = i / PH, k = i - j * PH;
    wGl[j * 322 + k] = w_g[(size_t)k * JH + cg * 8 + j];
  }
  for (int i = tid; i < 29 * 20; i += NTHR) {
    int v = i / 20, ci = i - v * 20;
    int col = (ci / 5) * PH + cg * 5 + (ci % 5);
    float acc = b0[col];
    for (int k = 0; k < PH; ++k)
      acc = fmaf(embed[v * PH + k], w_ih0[(size_t)k * G4 + col], acc);
    e0[v * 20 + ci] = acc;
  }
  __syncthreads();

  // owner-WG (cg < 32) scalar decoder state, held by tid 0
  int preg_reg = 0, idx_reg = 0, time_reg = 0, len_reg = 0, r_reg = NSTEPS,
      eos_reg = 0;
  if (cg < BPG && tid == 0) eos_reg = f_lens[b0i + cg] - 1;

  // ---------------- 400 free-running steps ----------------
  for (int s = 0; s < NSTEPS; ++s) {
    // ===== Phase A: LSTM0 =====
    if (tid < 4 * BPG) {            // one coalesced read of [32][4] scalars
      int bb = tid >> 2, fld = tid & 3;
      ibuf[fld * 32 + bb] = wsi[PST_O + (b0i + bb) * 4 + fld];
    }
    __syncthreads();
    stage32x(hb, wsf + H0_O, ibuf + 32, 0, b0i, tid);
    __syncthreads();
    {
      int b = tid & 31, ci = tid >> 5;          // 640 dots
      float acc = dot320(hb + b * 322, wA + ci * 322);
      gbuf[b * 20 + ci] = acc + e0[ibuf[b] * 20 + ci];
    }
    __syncthreads();
    if (tid < 160) {
      int b = tid & 31, u = tid >> 5;
      int p = cg * 5 + u, gb = b0i + b, bf = ibuf[32 + b];
      float gi = gbuf[b*20 + u],      gf = gbuf[b*20 + 5 + u];
      float gg = gbuf[b*20 + 10 + u], go = gbuf[b*20 + 15 + u];
      float c  = wsf[C0_O + (size_t)bf * SB + gb * PH + p];
      float cn = sigm(gf) * c + sigm(gi) * tanhf(gg);
      float hn = sigm(go) * tanhf(cn);
      wsf[H0_O + (size_t)(bf ^ 1) * SB + gb * PH + p] = hn;
      wsf[C0_O + (size_t)(bf ^ 1) * SB + gb * PH + p] = cn;
    }
    bar_flags(gfl, WGPG, cg, 4 * s + 1);

    // ===== Phase B: LSTM1 =====
    {
      stage32x(hb, wsf + H0_O, ibuf + 32, 1, b0i, tid);   // h0n (next buf)
      __syncthreads();
      int b = tid & 31, ci = tid >> 5;
      float accB = dot320(hb + b * 322, wB + ci * 642);
      __syncthreads();
      stage32x(hb, wsf + H1_O, ibuf + 32, 0, b0i, tid);   // h1 (cur buf)
      __syncthreads();
      int col = (ci / 5) * PH + cg * 5 + (ci % 5);
      accB += dot320(hb + b * 322, wB + ci * 642 + PH);
      gbuf[b * 20 + ci] = accB + b1[col];
    }
    __syncthreads();
    if (tid < 160) {
      int b = tid & 31, u = tid >> 5;
      int q = cg * 5 + u, gb = b0i + b, bf = ibuf[32 + b];
      float gi = gbuf[b*20 + u],      gf = gbuf[b*20 + 5 + u];
      float gg = gbuf[b*20 + 10 + u], go = gbuf[b*20 + 15 + u];
      float c  = wsf[C1_O + (size_t)bf * SB + gb * PH + q];
      float cn = sigm(gf) * c + sigm(gi) * tanhf(gg);
      float hn = sigm(go) * tanhf(cn);
      wsf[H1_O + (size_t)(bf ^ 1) * SB + gb * PH + q] = hn;
      wsf[C1_O + (size_t)(bf ^ 1) * SB + gb * PH + q] = cn;
    }
    bar_flags(gfl, WGPG, cg, 4 * s + 2);

    // ===== Phase C: Fp refresh (rare, LDS-driven flags) + joint relu =====
    for (int bb = 0; bb < BPG; ++bb) {
      if (ibuf[64 + bb]) {                    // tch flag, WG-uniform
        int gb = b0i + bb, t = ibuf[96 + bb];
        const float* fr = f + ((size_t)t * B_DIM + gb) * FH;
        for (int i = tid; i < FH; i += NTHR) frow[i] = fr[i];
        __syncthreads();
        if (tid < 512) {
          int j = tid & 7, kg = tid >> 3;
          float part = 0.f;
#pragma unroll 4
          for (int it = 0; it < FH / 64; ++it) {
            int kk = kg + it * 64;
            part = fmaf(frow[kk], w_f[(size_t)kk * JH + cg * 8 + j], part);
          }
          red[tid] = part;
        }
        __syncthreads();
        if (tid < 8) {
          float sum = 0.f;
          for (int kg = 0; kg < 64; ++kg) sum += red[kg * 8 + tid];
          wsf[FP_O + gb * JH + cg * 8 + tid] = sum + b_j[cg * 8 + tid];
        }
        __syncthreads();
      }
    }
    stage32x(hb, wsf + H1_O, ibuf + 32, 1, b0i, tid);     // h1n (next buf)
    __syncthreads();
    if (tid < 256) {
      int b = tid & 31, j = tid >> 5;
      int gb = b0i + b, jg = cg * 8 + j;
      float acc = dot320(hb + b * 322, wGl + j * 322);
      float v = wsf[FP_O + gb * JH + jg] + acc;
      wsf[JR_O + gb * JH + jg] = v > 0.f ? v : 0.f;
    }
    bar_flags(gfl, WGPG, cg, 4 * s + 3);

    // ===== Phase D: logits, argmax, scalar-state update (owner WGs) =====
    if (cg < BPG) {
      int b = b0i + cg;
      for (int i = tid; i < JH; i += NTHR) frow[i] = wsf[JR_O + b * JH + i];
      __syncthreads();
      if (tid < 512) {
        int v = tid & 31, jg = tid >> 5;
        float part = 0.f;
        if (v < NV) {
          const float* wop = w_o + (size_t)(jg * 32) * NV + v;
#pragma unroll 8
          for (int jj = 0; jj < 32; ++jj)
            part = fmaf(frow[jg * 32 + jj], wop[(size_t)jj * NV], part);
        }
        red[tid] = part;
      }
      __syncthreads();
      if (tid < NV) {
        float y = b_o[tid];
#pragma unroll
        for (int jg = 0; jg < 16; ++jg) y += red[jg * 32 + tid];
        out[((size_t)s * B_DIM + b) * NV + tid] = y;
        gbuf[tid] = y;
      }
      __syncthreads();
      if (tid == 0) {
        float best = gbuf[0]; int bi = 0;
        for (int v = 1; v < NV; ++v) {        // np.argmax: first max
          float yv = gbuf[v];
          if (yv > best) { best = yv; bi = v; }
        }
        int nb = (bi != BLANKSYM) ? 1 : 0;
        unsigned logw = 0u;
        if (nb) {
          int pos = len_reg < (MAXLEN - 1) ? len_reg : (MAXLEN - 1);
          logw = 0x80000000u | ((unsigned)pos << 8) | (unsigned)bi;
          len_reg++;
          preg_reg = bi;
          idx_reg ^= 1;                       // commit = flip ping-pong bit
        }
        wsi[LOG_O + b * NSTEPS + s] = (int)logw;
        int tnew = time_reg + (nb ? 0 : 1);
        if (tnew > eos_reg) tnew = eos_reg;
        int* ps = wsi + PST_O + b * 4;
        ps[0] = preg_reg;
        ps[1] = idx_reg;
        ps[2] = (tnew != time_reg) ? 1 : 0;
        ps[3] = tnew;
        if (r_reg == NSTEPS && tnew == eos_reg) r_reg = s;
        time_reg = tnew;
      }
    }
    bar_flags(gfl, WGPG, cg, 4 * s + 4);
  }

  // ---------------- epilogue: finished-flag fixup ----------------
  if (cg < BPG && tid == 0) wsi[R_O + b0i + cg] = r_reg;
  bar_flags(afl, NWG, wg, 1);

  if (tid < B_DIM) ((int*)red)[tid] = wsi[R_O + tid];
  __syncthreads();
  if (tid == 0) {
    int m = 0;
    for (int i = 0; i < B_DIM; ++i) m = max(m, ((int*)red)[i]);
    ibuf[129] = m;
  }
  __syncthreads();
  const int sstar = ibuf[129];
  __syncthreads();

  // ys tail: steps >= sstar+2 all equal ys[sstar+1]
  if (sstar <= NSTEPS - 3) {
    const size_t srcbase = (size_t)(sstar + 1) * B_DIM * NV;
    const size_t start = (size_t)(sstar + 2) * B_DIM * NV;
    const size_t total = (size_t)(NSTEPS - 2 - sstar) * B_DIM * NV;
    for (size_t i = (size_t)wg * NTHR + tid; i < total; i += (size_t)NWG * NTHR) {
      size_t r = i % (size_t)(B_DIM * NV);
      out[start + i] = out[srcbase + r];
    }
  }

  // tokens + out_lens: replay log entries for steps <= min(sstar, 399)
  if (wg < B_DIM) {
    int b = wg;
    int* lbuf = (int*)red;
    for (int i = tid; i < NSTEPS; i += NTHR) lbuf[i] = wsi[LOG_O + b * NSTEPS + i];
    if (tid < MAXLEN) frow[tid] = (float)BLANKSYM;
    __syncthreads();
    if (tid == 0) {
      int len = 0;
      int smax = sstar < NSTEPS - 1 ? sstar : NSTEPS - 1;
      for (int ss = 0; ss <= smax; ++ss) {
        unsigned uw = (unsigned)lbuf[ss];
        if (uw >> 31) {
          int pos = (int)((uw >> 8) & 0xFFu);
          int sym = (int)(uw & 0x1Fu);
          frow[pos] = (float)sym;
          len++;
        }
      }
      ibuf[130] = len;
    }
    __syncthreads();
    if (tid < MAXLEN) out[TOK_O + b * MAXLEN + tid] = frow[tid];
    if (tid == 0) out[LEN_O + b] = (float)ibuf[130];
  }
}

extern "C" void kernel_launch(void* const* d_in, const int* in_sizes, int n_in,
                              void* d_out, int out_size, void* d_ws, size_t ws_size,
                              hipStream_t stream) {
  const float* f      = (const float*)d_in[0];
  const int*   f_lens = (const int*)d_in[1];
  const float* embed  = (const float*)d_in[2];
  const float* w_ih0  = (const float*)d_in[3];
  const float* w_hh0  = (const float*)d_in[4];
  const float* b0     = (const float*)d_in[5];
  const float* w_ih1  = (const float*)d_in[6];
  const float* w_hh1  = (const float*)d_in[7];
  const float* b1     = (const float*)d_in[8];
  const float* w_f    = (const float*)d_in[9];
  const float* w_g    = (const float*)d_in[10];
  const float* b_j    = (const float*)d_in[11];
  const float* w_o    = (const float*)d_in[12];
  const float* b_o    = (const float*)d_in[13];
  float* out = (float*)d_out;
  float* wsf = (float*)d_ws;
  int*   wsi = (int*)(wsf + WSF_TOT);

  hipFuncSetAttribute((const void*)decode_main,
                      hipFuncAttributeMaxDynamicSharedMemorySize,
                      (int)(LDS_FLOATS * sizeof(float)));

  init_k<<<64, 256, 0, stream>>>(wsf, wsi);
  decode_main<<<dim3(NWG), dim3(NTHR), LDS_FLOATS * sizeof(float), stream>>>(
      f, f_lens, embed, w_ih0, w_hh0, b0, w_ih1, w_hh1, b1,
      w_f, w_g, b_j, w_o, b_o, out, wsf, wsi);
}

// Round 4
// 18357.509 us; speedup vs baseline: 3.3716x; 2.0668x over previous
//
#include <hip/hip_runtime.h>
#include <hip/hip_bf16.h>
#include <cstdint>
#include <cstddef>

// ---------------------------------------------------------------------------
// RNN-T greedy decoder, MI355X persistent cooperative kernel.  R4.
//
//  R3 post-mortem: 94.8us/step, VALUBusy 15.9% -> residual is barrier
//  mechanics: __threadfence() in the barrier = buffer_wbl2/buffer_inv (full
//  per-XCD L2 writeback+invalidate) x8/step, plus serial Fp-refresh loop.
//  R4: (1) fence-FREE sync: all cross-WG data via RELAXED+AGENT atomics
//  (sc-flagged, bypass L2 to the IF$ coherence point); barrier = relaxed flag
//  store + relaxed poll; ordering from the s_waitcnt vmcnt(0) the compiler
//  emits before s_barrier.  L2 stays warm for weights/w_f/f.  One single
//  __threadfence() before the epilogue global barrier covers plain LOG/ys
//  stores.  (2) Fp refresh parallelized (chunks of 4 b's across all threads).
//  (3) early exit when all 128 b's reached eos (group-uniform broadcast slot).
// ---------------------------------------------------------------------------

#define T_DIM 200
#define B_DIM 128
#define FH 1024
#define PH 320
#define G4 1280
#define JH 512
#define NV 29
#define BLANKSYM 28
#define NSTEPS 400
#define MAXLEN 256

#define NWG 256
#define NTHR 640
#define BPG 32      // batch elems per batch-group
#define WGPG 64     // workgroups per batch-group
#define SB (B_DIM*PH)

// ---- workspace float offsets ----
enum : int {
  H0_O = 0,                 // [2][B][PH] ping-pong
  C0_O = 2*SB,
  H1_O = 4*SB,
  C1_O = 6*SB,
  FP_O = 8*SB,              // [B][JH] cached fi@w_f + b_j
  JR_O = FP_O + B_DIM*JH,   // [B][JH] joint relu
  WSF_TOT = JR_O + B_DIM*JH
};
// ---- workspace int offsets ----
enum : int {
  R_O     = 0,                   // [B] first step time hits eos
  PST_O   = B_DIM,               // [B][4]: preg, idx, tch, timei
  REACH_O = PST_O + 4*B_DIM,     // [1] count of b's that reached eos (pad 16)
  GSTOP_O = REACH_O + 16,        // [4][16] per-group stop broadcast
  FLAG_O  = GSTOP_O + 64,        // [4][WGPG][4] group barrier flags
  GFLAG_O = FLAG_O + 4*WGPG*4,   // [NWG][4] global barrier flags
  LOG_O   = GFLAG_O + NWG*4,     // [B][NSTEPS] token log
  WSI_TOT = LOG_O + B_DIM*NSTEPS
};
// ---- output offsets (floats) ----
enum : int { TOK_O = NSTEPS*B_DIM*NV, LEN_O = TOK_O + B_DIM*MAXLEN };

// ---- LDS layout (floats) ----
#define WA_F  (20*322)   // w_hh0 cols [20][322]
#define WB_F  (20*642)   // w_ih1|w_hh1 cols [20][642]
#define WGG_F (8*322)    // w_g cols [8][322]
#define E0_F  (29*20)    // E0 slice
#define HB_F  (32*322)   // staged h slice / refresh partials
#define GB_F  640        // gate buffer / ybuf
#define FR_F  4096       // 4 f-rows (refresh) / JR stage / token buf
#define RED_F 640        // reductions / log buf
#define IB_F  192        // ints: [0..31] preg [32..63] idx [64..95] tch
                         // [96..127] timei [129] sstar [130] len
                         // [131..162] ref list [163] ref cnt [164] fin
#define LDS_FLOATS (WA_F+WB_F+WGG_F+E0_F+HB_F+GB_F+FR_F+RED_F+IB_F)

__device__ __forceinline__ float sigm(float x) { return 1.0f / (1.0f + expf(-x)); }

// ---- relaxed agent-scope (IF$-coherent, L1/L2-bypassing) accessors ----
__device__ __forceinline__ float gload(const float* p) {
  return __hip_atomic_load((float*)p, __ATOMIC_RELAXED, __HIP_MEMORY_SCOPE_AGENT);
}
__device__ __forceinline__ void gstore(float* p, float v) {
  __hip_atomic_store(p, v, __ATOMIC_RELAXED, __HIP_MEMORY_SCOPE_AGENT);
}
__device__ __forceinline__ int gload_i(const int* p) {
  return __hip_atomic_load((int*)p, __ATOMIC_RELAXED, __HIP_MEMORY_SCOPE_AGENT);
}
__device__ __forceinline__ void gstore_i(int* p, int v) {
  __hip_atomic_store(p, v, __ATOMIC_RELAXED, __HIP_MEMORY_SCOPE_AGENT);
}
__device__ __forceinline__ float2 gload2(const float* p) {
  unsigned long long u = __hip_atomic_load((unsigned long long*)p,
                                           __ATOMIC_RELAXED,
                                           __HIP_MEMORY_SCOPE_AGENT);
  float2 r; __builtin_memcpy(&r, &u, 8); return r;
}
__device__ __forceinline__ void gstore2(float* p, float2 v) {
  unsigned long long u; __builtin_memcpy(&u, &v, 8);
  __hip_atomic_store((unsigned long long*)p, u, __ATOMIC_RELAXED,
                     __HIP_MEMORY_SCOPE_AGENT);
}

// Fence-free flag barrier.  All stores of this WG are drained by the
// compiler-emitted s_waitcnt vmcnt(0) before s_barrier (agent-scope stores
// complete at the coherence point); flag store + polls are relaxed agent ops.
__device__ __forceinline__ void bar_flags(int* flags, int nf, int rank, int gen) {
  __syncthreads();
  if (threadIdx.x == 0)
    __hip_atomic_store(flags + rank * 4, gen, __ATOMIC_RELAXED,
                       __HIP_MEMORY_SCOPE_AGENT);
  if (threadIdx.x < nf) {
    while (__hip_atomic_load(flags + threadIdx.x * 4, __ATOMIC_RELAXED,
                             __HIP_MEMORY_SCOPE_AGENT) < gen)
      __builtin_amdgcn_s_sleep(1);
  }
  __syncthreads();
}

// stage a [32][PH] slice into hb[32][322], per-b ping-pong buffer select
__device__ __forceinline__ void stage32x(float* __restrict__ hb,
                                         const float* __restrict__ base,
                                         const int* __restrict__ idxv, int sel,
                                         int b0i, int tid) {
  for (int i = tid; i < BPG * (PH/2); i += NTHR) {
    int b  = i / (PH/2);
    int k2 = i - b * (PH/2);
    int bf = idxv[b] ^ sel;
    *(float2*)(hb + b*322 + 2*k2) =
        gload2(base + ((size_t)bf * B_DIM + b0i + b) * PH + 2*k2);
  }
}

__device__ __forceinline__ float dot320(const float* __restrict__ h,
                                        const float* __restrict__ w) {
  float a0 = 0.f, a1 = 0.f, a2 = 0.f, a3 = 0.f;
  const float2* h2 = (const float2*)h;
  const float2* w2 = (const float2*)w;
#pragma unroll 4
  for (int k = 0; k < 160; k += 4) {
    float2 x0 = h2[k+0], x1 = h2[k+1], x2 = h2[k+2], x3 = h2[k+3];
    float2 y0 = w2[k+0], y1 = w2[k+1], y2 = w2[k+2], y3 = w2[k+3];
    a0 = fmaf(x0.x, y0.x, a0); a0 = fmaf(x0.y, y0.y, a0);
    a1 = fmaf(x1.x, y1.x, a1); a1 = fmaf(x1.y, y1.y, a1);
    a2 = fmaf(x2.x, y2.x, a2); a2 = fmaf(x2.y, y2.y, a2);
    a3 = fmaf(x3.x, y3.x, a3); a3 = fmaf(x3.y, y3.y, a3);
  }
  return (a0 + a1) + (a2 + a3);
}

__global__ void init_k(float* wsf, int* wsi) {
  int i = blockIdx.x * blockDim.x + threadIdx.x;
  int n = blockDim.x * gridDim.x;
  for (int x = i; x < 8 * SB; x += n) wsf[x] = 0.f;  // both ping-pong bufs
  for (int x = i; x < B_DIM; x += n) {
    wsi[R_O + x] = NSTEPS;
    wsi[PST_O + x*4 + 0] = 0;   // preg
    wsi[PST_O + x*4 + 1] = 0;   // idx
    wsi[PST_O + x*4 + 2] = 1;   // tch: force Fp compute at step 0
    wsi[PST_O + x*4 + 3] = 0;   // timei
  }
  for (int x = i; x < 16 + 64 + 4*WGPG*4 + NWG*4; x += n)
    wsi[REACH_O + x] = 0;
}

__global__ void __launch_bounds__(NTHR) decode_main(
    const float* __restrict__ f, const int* __restrict__ f_lens,
    const float* __restrict__ embed,
    const float* __restrict__ w_ih0, const float* __restrict__ w_hh0,
    const float* __restrict__ b0,
    const float* __restrict__ w_ih1, const float* __restrict__ w_hh1,
    const float* __restrict__ b1,
    const float* __restrict__ w_f, const float* __restrict__ w_g,
    const float* __restrict__ b_j,
    const float* __restrict__ w_o, const float* __restrict__ b_o,
    float* __restrict__ out, float* __restrict__ wsf, int* __restrict__ wsi) {
  extern __shared__ float smem[];
  float* wA   = smem;
  float* wB   = wA + WA_F;
  float* wGl  = wB + WB_F;
  float* e0   = wGl + WGG_F;
  float* hb   = e0 + E0_F;
  float* gbuf = hb + HB_F;
  float* frow = gbuf + GB_F;
  float* red  = frow + FR_F;
  int*   ibuf = (int*)(red + RED_F);

  const int tid = threadIdx.x;
  const int wg  = blockIdx.x;
  const int bg  = wg >> 6;       // batch-group 0..3
  const int cg  = wg & 63;       // column-group 0..63
  const int b0i = bg * BPG;
  int* gfl = wsi + FLAG_O + bg * WGPG * 4;   // group barrier flags
  int* afl = wsi + GFLAG_O;                  // global barrier flags

  // ---------------- prologue: load weight slices into LDS ----------------
  for (int i = tid; i < 20 * PH; i += NTHR) {
    int ci = i / PH, k = i - ci * PH;
    int col = (ci / 5) * PH + cg * 5 + (ci % 5);
    wA[ci * 322 + k] = w_hh0[(size_t)k * G4 + col];
  }
  for (int i = tid; i < 20 * 2 * PH; i += NTHR) {
    int ci = i / (2 * PH), k = i - ci * 2 * PH;
    int col = (ci / 5) * PH + cg * 5 + (ci % 5);
    wB[ci * 642 + k] = (k < PH) ? w_ih1[(size_t)k * G4 + col]
                                : w_hh1[(size_t)(k - PH) * G4 + col];
  }
  for (int i = tid; i < 8 * PH; i += NTHR) {
    int j = i / PH, k = i - j * PH;
    wGl[j * 322 + k] = w_g[(size_t)k * JH + cg * 8 + j];
  }
  for (int i = tid; i < 29 * 20; i += NTHR) {
    int v = i / 20, ci = i - v * 20;
    int col = (ci / 5) * PH + cg * 5 + (ci % 5);
    float acc = b0[col];
    for (int k = 0; k < PH; ++k)
      acc = fmaf(embed[v * PH + k], w_ih0[(size_t)k * G4 + col], acc);
    e0[v * 20 + ci] = acc;
  }
  __syncthreads();

  // owner-WG (cg < 32) scalar decoder state, held by tid 0
  int preg_reg = 0, idx_reg = 0, time_reg = 0, len_reg = 0, r_reg = NSTEPS,
      eos_reg = 0;
  if (cg < BPG && tid == 0) eos_reg = f_lens[b0i + cg] - 1;

  int genc = 0;

  // ---------------- free-running steps (early exit when all reach eos) ----
  for (int s = 0; s < NSTEPS; ++s) {
    // ===== Phase A: LSTM0 =====
    if (tid < 4 * BPG) {            // one coalesced read of [32][4] scalars
      int bb = tid >> 2, fld = tid & 3;
      ibuf[fld * 32 + bb] = gload_i(wsi + PST_O + (b0i + bb) * 4 + fld);
    }
    if (cg == 0 && tid == 0) {      // group-uniform stop broadcast (read in B)
      int fin = (gload_i(wsi + REACH_O) == B_DIM) ? 1 : 0;
      gstore_i(wsi + GSTOP_O + bg * 16, fin);
    }
    __syncthreads();
    stage32x(hb, wsf + H0_O, ibuf + 32, 0, b0i, tid);
    __syncthreads();
    {
      int b = tid & 31, ci = tid >> 5;          // 640 dots
      float acc = dot320(hb + b * 322, wA + ci * 322);
      gbuf[b * 20 + ci] = acc + e0[ibuf[b] * 20 + ci];
    }
    __syncthreads();
    if (tid < 160) {
      int b = tid & 31, u = tid >> 5;
      int p = cg * 5 + u, gb = b0i + b, bf = ibuf[32 + b];
      float gi = gbuf[b*20 + u],      gf = gbuf[b*20 + 5 + u];
      float gg = gbuf[b*20 + 10 + u], go = gbuf[b*20 + 15 + u];
      float c  = gload(wsf + C0_O + (size_t)bf * SB + gb * PH + p);
      float cn = sigm(gf) * c + sigm(gi) * tanhf(gg);
      float hn = sigm(go) * tanhf(cn);
      gstore(wsf + H0_O + (size_t)(bf ^ 1) * SB + gb * PH + p, hn);
      gstore(wsf + C0_O + (size_t)(bf ^ 1) * SB + gb * PH + p, cn);
    }
    bar_flags(gfl, WGPG, cg, ++genc);

    // ===== Phase B: LSTM1 =====
    {
      stage32x(hb, wsf + H0_O, ibuf + 32, 1, b0i, tid);   // h0n (next buf)
      if (tid == 0) ibuf[164] = gload_i(wsi + GSTOP_O + bg * 16);
      __syncthreads();
      int b = tid & 31, ci = tid >> 5;
      float accB = dot320(hb + b * 322, wB + ci * 642);
      __syncthreads();
      stage32x(hb, wsf + H1_O, ibuf + 32, 0, b0i, tid);   // h1 (cur buf)
      __syncthreads();
      int col = (ci / 5) * PH + cg * 5 + (ci % 5);
      accB += dot320(hb + b * 322, wB + ci * 642 + PH);
      gbuf[b * 20 + ci] = accB + b1[col];
    }
    const int fin = ibuf[164];
    __syncthreads();
    if (tid < 160) {
      int b = tid & 31, u = tid >> 5;
      int q = cg * 5 + u, gb = b0i + b, bf = ibuf[32 + b];
      float gi = gbuf[b*20 + u],      gf = gbuf[b*20 + 5 + u];
      float gg = gbuf[b*20 + 10 + u], go = gbuf[b*20 + 15 + u];
      float c  = gload(wsf + C1_O + (size_t)bf * SB + gb * PH + q);
      float cn = sigm(gf) * c + sigm(gi) * tanhf(gg);
      float hn = sigm(go) * tanhf(cn);
      gstore(wsf + H1_O + (size_t)(bf ^ 1) * SB + gb * PH + q, hn);
      gstore(wsf + C1_O + (size_t)(bf ^ 1) * SB + gb * PH + q, cn);
    }
    bar_flags(gfl, WGPG, cg, ++genc);

    // ===== Phase C: parallel Fp refresh + joint relu =====
    if (tid == 0) {
      int cnt = 0;
      for (int bb = 0; bb < BPG; ++bb)
        if (ibuf[64 + bb]) ibuf[131 + cnt++] = bb;
      ibuf[163] = cnt;
    }
    __syncthreads();
    const int nref = ibuf[163];
    for (int chunk = 0; chunk < nref; chunk += 4) {
      int nc = nref - chunk; if (nc > 4) nc = 4;
      for (int i = tid; i < nc * FH; i += NTHR) {   // stage nc f-rows
        int c = i >> 10, ii = i & 1023;
        int bb = ibuf[131 + chunk + c];
        int t  = ibuf[96 + bb];
        frow[c * FH + ii] = f[((size_t)t * B_DIM + (b0i + bb)) * FH + ii];
      }
      __syncthreads();
      if (tid < 512) {
        int j = tid & 7, kg = tid >> 3;
        float a0 = 0.f, a1 = 0.f, a2 = 0.f, a3 = 0.f;
        const float* wf = w_f + cg * 8 + j;
#pragma unroll
        for (int kk = 0; kk < 16; ++kk) {
          int k = kg * 16 + kk;
          float wv = wf[(size_t)k * JH];             // reused across rows
          a0 = fmaf(frow[k], wv, a0);
          a1 = fmaf(frow[FH + k], wv, a1);
          a2 = fmaf(frow[2*FH + k], wv, a2);
          a3 = fmaf(frow[3*FH + k], wv, a3);
        }
        hb[0*512 + tid] = a0; hb[1*512 + tid] = a1;  // partials (hb free here)
        hb[2*512 + tid] = a2; hb[3*512 + tid] = a3;
      }
      __syncthreads();
      if (tid < nc * 8) {
        int c = tid >> 3, j = tid & 7;
        float sum = 0.f;
        for (int kg = 0; kg < 64; ++kg) sum += hb[c * 512 + kg * 8 + j];
        int bb = ibuf[131 + chunk + c];
        gstore(wsf + FP_O + (b0i + bb) * JH + cg * 8 + j, sum + b_j[cg * 8 + j]);
      }
      __syncthreads();
    }
    stage32x(hb, wsf + H1_O, ibuf + 32, 1, b0i, tid);     // h1n (next buf)
    __syncthreads();
    if (tid < 256) {
      int b = tid & 31, j = tid >> 5;
      int gb = b0i + b, jg = cg * 8 + j;
      float acc = dot320(hb + b * 322, wGl + j * 322);
      float v = gload(wsf + FP_O + gb * JH + jg) + acc;
      gstore(wsf + JR_O + gb * JH + jg, v > 0.f ? v : 0.f);
    }
    bar_flags(gfl, WGPG, cg, ++genc);

    // ===== Phase D: logits, argmax, scalar-state update (owner WGs) =====
    if (cg < BPG) {
      int b = b0i + cg;
      for (int i = tid; i < JH/2; i += NTHR)
        *(float2*)(frow + 2*i) = gload2(wsf + JR_O + b * JH + 2*i);
      __syncthreads();
      if (tid < 512) {
        int v = tid & 31, jg = tid >> 5;
        float part = 0.f;
        if (v < NV) {
          const float* wop = w_o + (size_t)(jg * 32) * NV + v;
#pragma unroll 8
          for (int jj = 0; jj < 32; ++jj)
            part = fmaf(frow[jg * 32 + jj], wop[(size_t)jj * NV], part);
        }
        red[tid] = part;
      }
      __syncthreads();
      if (tid < NV) {
        float y = b_o[tid];
#pragma unroll
        for (int jg = 0; jg < 16; ++jg) y += red[jg * 32 + tid];
        out[((size_t)s * B_DIM + b) * NV + tid] = y;
        gbuf[tid] = y;
      }
      __syncthreads();
      if (tid == 0) {
        float best = gbuf[0]; int bi = 0;
        for (int v = 1; v < NV; ++v) {        // np.argmax: first max
          float yv = gbuf[v];
          if (yv > best) { best = yv; bi = v; }
        }
        int nb = (bi != BLANKSYM) ? 1 : 0;
        unsigned logw = 0u;
        if (nb) {
          int pos = len_reg < (MAXLEN - 1) ? len_reg : (MAXLEN - 1);
          logw = 0x80000000u | ((unsigned)pos << 8) | (unsigned)bi;
          len_reg++;
          preg_reg = bi;
          idx_reg ^= 1;                       // commit = flip ping-pong bit
        }
        wsi[LOG_O + b * NSTEPS + s] = (int)logw;   // plain (epilogue-fenced)
        int tnew = time_reg + (nb ? 0 : 1);
        if (tnew > eos_reg) tnew = eos_reg;
        int* ps = wsi + PST_O + b * 4;
        gstore_i(ps + 0, preg_reg);
        gstore_i(ps + 1, idx_reg);
        gstore_i(ps + 2, (tnew != time_reg) ? 1 : 0);
        gstore_i(ps + 3, tnew);
        if (r_reg == NSTEPS && tnew == eos_reg) {
          r_reg = s;
          __hip_atomic_fetch_add(wsi + REACH_O, 1, __ATOMIC_RELAXED,
                                 __HIP_MEMORY_SCOPE_AGENT);
        }
        time_reg = tnew;
      }
    }
    bar_flags(gfl, WGPG, cg, ++genc);
    if (fin) break;     // observed all-reached at A_s => s >= sstar+1; done
  }

  // ---------------- epilogue: finished-flag fixup ----------------
  if (cg < BPG && tid == 0) gstore_i(wsi + R_O + b0i + cg, r_reg);
  __syncthreads();
  if (tid == 0) __threadfence();   // flush plain LOG/ys stores (wbl2, once)
  bar_flags(afl, NWG, wg, 1);

  if (tid < B_DIM) ((int*)red)[tid] = gload_i(wsi + R_O + tid);
  __syncthreads();
  if (tid == 0) {
    int m = 0;
    for (int i = 0; i < B_DIM; ++i) m = max(m, ((int*)red)[i]);
    ibuf[129] = m;
  }
  __syncthreads();
  const int sstar = ibuf[129];
  __syncthreads();

  // ys tail: steps >= sstar+2 all equal ys[sstar+1]
  if (sstar <= NSTEPS - 3) {
    const size_t srcbase = (size_t)(sstar + 1) * B_DIM * NV;
    const size_t start = (size_t)(sstar + 2) * B_DIM * NV;
    const size_t total = (size_t)(NSTEPS - 2 - sstar) * B_DIM * NV;
    for (size_t i = (size_t)wg * NTHR + tid; i < total; i += (size_t)NWG * NTHR) {
      size_t r = i % (size_t)(B_DIM * NV);
      out[start + i] = gload(out + srcbase + r);   // bypass (cross-XCD writer)
    }
  }

  // tokens + out_lens: replay log entries for steps <= min(sstar, 399)
  if (wg < B_DIM) {
    int b = wg;
    int* lbuf = (int*)red;
    for (int i = tid; i < NSTEPS; i += NTHR)
      lbuf[i] = gload_i(wsi + LOG_O + b * NSTEPS + i);
    if (tid < MAXLEN) frow[tid] = (float)BLANKSYM;
    __syncthreads();
    if (tid == 0) {
      int len = 0;
      int smax = sstar < NSTEPS - 1 ? sstar : NSTEPS - 1;
      for (int ss = 0; ss <= smax; ++ss) {
        unsigned uw = (unsigned)lbuf[ss];
        if (uw >> 31) {
          int pos = (int)((uw >> 8) & 0xFFu);
          int sym = (int)(uw & 0x1Fu);
          frow[pos] = (float)sym;
          len++;
        }
      }
      ibuf[130] = len;
    }
    __syncthreads();
    if (tid < MAXLEN) out[TOK_O + b * MAXLEN + tid] = frow[tid];
    if (tid == 0) out[LEN_O + b] = (float)ibuf[130];
  }
}

extern "C" void kernel_launch(void* const* d_in, const int* in_sizes, int n_in,
                              void* d_out, int out_size, void* d_ws, size_t ws_size,
                              hipStream_t stream) {
  const float* f      = (const float*)d_in[0];
  const int*   f_lens = (const int*)d_in[1];
  const float* embed  = (const float*)d_in[2];
  const float* w_ih0  = (const float*)d_in[3];
  const float* w_hh0  = (const float*)d_in[4];
  const float* b0     = (const float*)d_in[5];
  const float* w_ih1  = (const float*)d_in[6];
  const float* w_hh1  = (const float*)d_in[7];
  const float* b1     = (const float*)d_in[8];
  const float* w_f    = (const float*)d_in[9];
  const float* w_g    = (const float*)d_in[10];
  const float* b_j    = (const float*)d_in[11];
  const float* w_o    = (const float*)d_in[12];
  const float* b_o    = (const float*)d_in[13];
  float* out = (float*)d_out;
  float* wsf = (float*)d_ws;
  int*   wsi = (int*)(wsf + WSF_TOT);

  hipFuncSetAttribute((const void*)decode_main,
                      hipFuncAttributeMaxDynamicSharedMemorySize,
                      (int)(LDS_FLOATS * sizeof(float)));

  init_k<<<64, 256, 0, stream>>>(wsf, wsi);
  decode_main<<<dim3(NWG), dim3(NTHR), LDS_FLOATS * sizeof(float), stream>>>(
      f, f_lens, embed, w_ih0, w_hh0, b0, w_ih1, w_hh1, b1,
      w_f, w_g, b_j, w_o, b_o, out, wsf, wsi);
}